// Round 6
// baseline (103.631 us; speedup 1.0000x reference)
//
#include <hip/hip_runtime.h>
#include <hip/hip_bf16.h>

#define EPG 342
#define WS_AOFF 32768      // ushort offset of A-matrix in ws (after 64KB W-bf16)

typedef short short8 __attribute__((ext_vector_type(8)));
typedef float f32x4  __attribute__((ext_vector_type(4)));

static __device__ __forceinline__ unsigned int f2bf(float f) {
    unsigned int u = __float_as_uint(f);
    return (u + 0x7fffu + ((u >> 16) & 1u)) >> 16;   // RNE
}
static __device__ __forceinline__ int pk2(float lo, float hi) {
    return (int)(f2bf(lo) | (f2bf(hi) << 16));
}

// ---------------- Kernel A: per-graph aggregation + bf16 pack ----------------
// One 128-thread block per graph. Writes packed A row-block: row r of graph g
// is wsA[(g*19+r)*256 + k], k in [0,128)=agg, [128,256)=x (bf16).
// Blocks 0..63 additionally convert Wrel|Wroot -> bf16 at ws[0..32768).
__global__ __launch_bounds__(128) void pack_agg(
    const float* __restrict__ x,
    const int*   __restrict__ ei,
    const float* __restrict__ ew,
    const float* __restrict__ Wrel,
    const float* __restrict__ Wroot,
    unsigned short* __restrict__ wsW,   // ws base (bf16 W, 32768 ushorts)
    unsigned short* __restrict__ wsA,   // ws + WS_AOFF
    int E_total)
{
    __shared__ unsigned short xs[19][136];   // 5168 B, row stride 272 B (16B-mult)
    __shared__ float adj[19][20];            // 1520 B

    const int t = threadIdx.x;
    const int g = blockIdx.x;

    // ---- fused W fp32->bf16 conversion (64 blocks x 128 thr x 1 float4) ----
    if (g < 64) {
        int tid4 = g * 128 + t;              // 0..8191 float4s over [Wrel|Wroot]
        const float* src = (tid4 < 4096) ? (Wrel + tid4 * 4)
                                         : (Wroot + (tid4 - 4096) * 4);
        float4 v = *(const float4*)src;
        int2 w; w.x = pk2(v.x, v.y); w.y = pk2(v.z, v.w);
        *(int2*)&wsW[tid4 * 4] = w;
    }

    // ---- P1: load x (coalesced float4), convert, -> LDS + ws x-half ----
    const float4* xg = (const float4*)(x + (size_t)g * 19 * 128);
    unsigned short* arow = wsA + (size_t)g * 19 * 256;
    for (int idx = t; idx < 608; idx += 128) {      // 19*32 float4s
        int row = idx >> 5, c4 = idx & 31;
        float4 v = xg[idx];
        int2 w; w.x = pk2(v.x, v.y); w.y = pk2(v.z, v.w);
        *(int2*)&xs[row][c4 * 4] = w;
        *(int2*)&arow[row * 256 + 128 + c4 * 4] = w;
    }
    for (int i = t; i < 380; i += 128) ((float*)adj)[i] = 0.f;
    __syncthreads();

    // ---- P2: scatter this graph's 342 edges ----
    for (int e = t; e < EPG; e += 128) {
        int ge = g * EPG + e;
        int sl = ei[ge] - g * 19;            // row 0: src
        int dl = ei[E_total + ge] - g * 19;  // row 1: dst
        adj[dl][sl] = ew[e];                 // rep[ge] = ew[ge % 342] = ew[e]
    }
    __syncthreads();

    // ---- P3: agg[j][c] = sum_i adj[j][i]*x[i][c] -> ws agg-half ----
    for (int idx = t; idx < 304; idx += 128) {      // 19 rows x 16 chunks
        int j = idx >> 4, c8 = idx & 15;
        float acc[8];
        #pragma unroll
        for (int q = 0; q < 8; ++q) acc[q] = 0.f;
        #pragma unroll 4
        for (int i = 0; i < 19; ++i) {
            float a = adj[j][i];
            int4 w = *(const int4*)&xs[i][c8 * 8];
            acc[0] += a * __uint_as_float((unsigned)w.x << 16);
            acc[1] += a * __uint_as_float((unsigned)w.x & 0xffff0000u);
            acc[2] += a * __uint_as_float((unsigned)w.y << 16);
            acc[3] += a * __uint_as_float((unsigned)w.y & 0xffff0000u);
            acc[4] += a * __uint_as_float((unsigned)w.z << 16);
            acc[5] += a * __uint_as_float((unsigned)w.z & 0xffff0000u);
            acc[6] += a * __uint_as_float((unsigned)w.w << 16);
            acc[7] += a * __uint_as_float((unsigned)w.w & 0xffff0000u);
        }
        int4 o;
        o.x = pk2(acc[0], acc[1]); o.y = pk2(acc[2], acc[3]);
        o.z = pk2(acc[4], acc[5]); o.w = pk2(acc[6], acc[7]);
        *(int4*)&arow[j * 256 + c8 * 8] = o;
    }
}

// ---------------- Kernel B: C[M x 128] = A[M x 256] * W^T + b ----------------
// M-tile 32 per 256-thread block. W already bf16 in ws.
__global__ __launch_bounds__(256) void gemm_out(
    const unsigned short* __restrict__ wsW,
    const unsigned short* __restrict__ wsA,
    const float* __restrict__ brel,
    float* __restrict__ out,
    int nrow)
{
    __shared__ __align__(16) unsigned short At[32 * 264];   // 16896 B, padded

    const int t    = threadIdx.x;
    const int lane = t & 63;
    const int wv   = t >> 6;
    const int row0 = blockIdx.x * 32;

    // ---- stage A-tile (reads past nrow hit ws poison: finite bf16, unstored) ----
    for (int idx = t; idx < 1024; idx += 256) {     // 32 rows x 32 int4
        int r = idx >> 5, c = idx & 31;
        int4 v = *(const int4*)&wsA[(size_t)(row0 + r) * 256 + c * 8];
        *(int4*)&At[r * 264 + c * 8] = v;
    }

    // ---- W fragments: lane holds B[k=kq+j][n=col] = W[col][kq+j] ----
    const int lrow = lane & 15;
    const int kq   = (lane >> 4) * 8;
    const int colA = wv * 16 + lrow;
    const int colB = (wv + 4) * 16 + lrow;

    short8 bf[2][2][4];
    #pragma unroll
    for (int pass = 0; pass < 2; ++pass)
        #pragma unroll
        for (int ct = 0; ct < 2; ++ct) {
            const unsigned short* wr = wsW + pass * 16384
                                     + (size_t)(ct ? colB : colA) * 128 + kq;
            #pragma unroll
            for (int ks = 0; ks < 4; ++ks)
                bf[pass][ct][ks] = *(const short8*)(wr + ks * 32);
        }
    const float bias0 = brel[colA];
    const float bias1 = brel[colB];
    __syncthreads();

    #pragma unroll
    for (int rt = 0; rt < 2; ++rt) {
        f32x4 acc0 = {0.f, 0.f, 0.f, 0.f};
        f32x4 acc1 = {0.f, 0.f, 0.f, 0.f};
        const unsigned short* ar = At + (rt * 16 + lrow) * 264 + kq;
        #pragma unroll
        for (int ks = 0; ks < 8; ++ks) {    // k: 0..127 rel, 128..255 root
            short8 a = *(const short8*)(ar + ks * 32);
            int p = ks >> 2, k4 = ks & 3;
            acc0 = __builtin_amdgcn_mfma_f32_16x16x32_bf16(a, bf[p][0][k4], acc0, 0, 0, 0);
            acc1 = __builtin_amdgcn_mfma_f32_16x16x32_bf16(a, bf[p][1][k4], acc1, 0, 0, 0);
        }
        // C/D layout: col = lane&15, row = (lane>>4)*4 + reg
        int rbase = row0 + rt * 16 + (lane >> 4) * 4;
        #pragma unroll
        for (int r = 0; r < 4; ++r) {
            int row = rbase + r;
            if (row < nrow) {
                out[(size_t)row * 128 + colA] = acc0[r] + bias0;
                out[(size_t)row * 128 + colB] = acc1[r] + bias1;
            }
        }
    }
}

extern "C" void kernel_launch(void* const* d_in, const int* in_sizes, int n_in,
                              void* d_out, int out_size, void* d_ws, size_t ws_size,
                              hipStream_t stream) {
    const float* x     = (const float*)d_in[0];
    const int*   ei    = (const int*)d_in[1];
    const float* ew    = (const float*)d_in[2];
    const float* Wrel  = (const float*)d_in[3];
    const float* brel  = (const float*)d_in[4];
    const float* Wroot = (const float*)d_in[5];
    float* out = (float*)d_out;

    unsigned short* wsW = (unsigned short*)d_ws;
    unsigned short* wsA = wsW + WS_AOFF;

    const int E_total  = in_sizes[1] / 2;     // 615600
    const int n_graphs = E_total / EPG;       // 1800
    const int nrow     = n_graphs * 19;       // 34200
    const int nb_gemm  = (nrow + 31) / 32;    // 1069

    pack_agg<<<n_graphs, 128, 0, stream>>>(x, ei, ew, Wrel, Wroot,
                                           wsW, wsA, E_total);
    gemm_out<<<nb_gemm, 256, 0, stream>>>(wsW, wsA, brel, out, nrow);
}

// Round 8
// 93.979 us; speedup vs baseline: 1.1027x; 1.1027x over previous
//
#include <hip/hip_runtime.h>
#include <hip/hip_bf16.h>

#define EPG 342
#define LDX 136   // Xs row stride (ushorts): 272 B, 16B-mult, bank-skewed
#define LDT 72    // T1T row stride (ushorts): 144 B, k-dim 0..63
#define LDA 40    // adj row stride (ushorts): 80 B, 16B-mult, bank-skewed

typedef short short8 __attribute__((ext_vector_type(8)));
typedef float f32x4  __attribute__((ext_vector_type(4)));

static __device__ __forceinline__ unsigned int f2bf(float f) {
    unsigned int u = __float_as_uint(f);
    return (u + 0x7fffu + ((u >> 16) & 1u)) >> 16;   // RNE
}
static __device__ __forceinline__ int pk2(float lo, float hi) {
    return (int)(f2bf(lo) | (f2bf(hi) << 16));
}

// ---- pre-kernel: W' = [Wrel ; Wroot] -> bf16 row-major [256][128] in ws ----
__global__ __launch_bounds__(256) void conv_w(
    const float* __restrict__ Wrel, const float* __restrict__ Wroot,
    unsigned short* __restrict__ wsW)
{
    int tid = blockIdx.x * 256 + threadIdx.x;        // 0..8191 float4s
    const float* src = (tid < 4096) ? (Wrel + tid * 4)
                                    : (Wroot + (tid - 4096) * 4);
    float4 v = *(const float4*)src;
    int2 w; w.x = pk2(v.x, v.y); w.y = pk2(v.z, v.w);
    *(int2*)&wsW[tid * 4] = w;
}

// ---- main: 2 graphs/block, all math via MFMA ----
// Stage-1: T[64x256] = Xs[64x128]·W'^T   (rows padded 32/graph, pad rows zero)
// Stage-2: out_g[19x128] = adj_g[19x32]·T1_g[32x128] + T2_g + bias
__global__ __launch_bounds__(256) void fused(
    const float* __restrict__ x,
    const int*   __restrict__ ei,
    const float* __restrict__ ew,
    const unsigned short* __restrict__ wsW,
    const float* __restrict__ brel,
    float* __restrict__ out,
    int E_total)
{
    __shared__ __align__(16) unsigned short Xs[64 * LDX];     // 17408 B
    __shared__ __align__(16) unsigned short T1T[128 * LDT];   // 18432 B (T1^T: [col][k])
    __shared__ __align__(16) unsigned short adj[2 * 32 * LDA];//  5120 B

    const int t    = threadIdx.x;
    const int lane = t & 63;
    const int wv   = t >> 6;
    const int g0   = blockIdx.x * 2;
    const int lrow = lane & 15;
    const int kq   = (lane >> 4) * 8;

    // ---- issue all global loads up front ----
    const float4* xg = (const float4*)(x + (size_t)g0 * 19 * 128);
    float4 xc[5];
    #pragma unroll
    for (int q = 0; q < 5; ++q) { int i = t + q * 256; if (i < 1216) xc[q] = xg[i]; }

    // W frags (bf16, zero convert VALU): wave w owns N-tiles {w, w+4, w+8, w+12}
    short8 wf[4][4];   // [ntile-local][k-step]
    #pragma unroll
    for (int nl = 0; nl < 4; ++nl) {
        int col = (wv + nl * 4) * 16 + lrow;         // 0..255
        #pragma unroll
        for (int ks = 0; ks < 4; ++ks)
            wf[nl][ks] = *(const short8*)&wsW[col * 128 + ks * 32 + kq];
    }

    int   e_d[3]; int e_s[3]; float e_w[3];
    #pragma unroll
    for (int q = 0; q < 3; ++q) {
        int e = t + q * 256;
        if (e < 2 * EPG) {
            int gg = (e >= EPG);
            int ge = g0 * EPG + e;
            e_s[q] = ei[ge] - (g0 + gg) * 19;                  // src 0..18
            e_d[q] = ei[E_total + ge] - (g0 + gg) * 19 + gg * 32;
            e_w[q] = ew[e - gg * EPG];                         // rep = ew[e%342]
        } else e_s[q] = -1;
    }
    const float b0 = brel[wv * 16 + lrow];
    const float b1 = brel[(wv + 4) * 16 + lrow];

    // ---- zero adj (FULL 320 int4) and Xs pad rows 19..31 per graph
    //      (26 rows x 16 int4 = 416 int4; R7 bug: only half was zeroed) ----
    {
        int4 z = {0, 0, 0, 0};
        for (int i = t; i < 320; i += 256) ((int4*)adj)[i] = z;
        for (int i = t; i < 416; i += 256) {
            int r = i >> 4, c = i & 15;              // r 0..25, c 0..15
            int g = (r >= 13); int lr = 19 + r - g * 13;
            *(int4*)&Xs[(g * 32 + lr) * LDX + c * 8] = z;
        }
    }
    __syncthreads();

    // ---- scatter edges (bf16 weights) + pack x into Xs rows 32g+0..18 ----
    #pragma unroll
    for (int q = 0; q < 3; ++q)
        if (e_s[q] >= 0) adj[e_d[q] * LDA + e_s[q]] = (unsigned short)f2bf(e_w[q]);
    #pragma unroll
    for (int q = 0; q < 5; ++q) {
        int i = t + q * 256;
        if (i < 1216) {
            int row = i >> 5, c4 = i & 31;
            int g = (row >= 19); int lr = row - g * 19;
            float4 v = xc[q];
            int2 w; w.x = pk2(v.x, v.y); w.y = pk2(v.z, v.w);
            *(int2*)&Xs[(g * 32 + lr) * LDX + c4 * 4] = w;
        }
    }
    __syncthreads();

    // ---- stage-1: 64 MFMA/wave ----
    f32x4 acc[4][4];   // [mtile][ntile-local]
    #pragma unroll
    for (int mt = 0; mt < 4; ++mt)
        #pragma unroll
        for (int nl = 0; nl < 4; ++nl) acc[mt][nl] = (f32x4){0.f, 0.f, 0.f, 0.f};

    #pragma unroll
    for (int ks = 0; ks < 4; ++ks) {
        short8 af[4];
        #pragma unroll
        for (int mt = 0; mt < 4; ++mt)
            af[mt] = *(const short8*)&Xs[(mt * 16 + lrow) * LDX + ks * 32 + kq];
        #pragma unroll
        for (int mt = 0; mt < 4; ++mt)
            #pragma unroll
            for (int nl = 0; nl < 4; ++nl)
                acc[mt][nl] = __builtin_amdgcn_mfma_f32_16x16x32_bf16(
                    af[mt], wf[nl][ks], acc[mt][nl], 0, 0, 0);
    }

    // ---- rel half (cols 0..127) -> T1T transposed; C-layout gives 4
    //      consecutive k per lane: one 8B write each ----
    #pragma unroll
    for (int mt = 0; mt < 4; ++mt)
        #pragma unroll
        for (int nl = 0; nl < 2; ++nl) {
            int col = (wv + nl * 4) * 16 + lrow;     // 0..127
            int r0  = mt * 16 + (lane >> 4) * 4;     // k index (block row)
            f32x4 a = acc[mt][nl];
            int2 w; w.x = pk2(a[0], a[1]); w.y = pk2(a[2], a[3]);
            *(int2*)&T1T[col * LDT + r0] = w;
        }
    __syncthreads();

    // ---- stage-2: out_g = adj_g · T1_g + T2 + bias (8 MFMA/wave) ----
    #pragma unroll
    for (int g = 0; g < 2; ++g) {
        #pragma unroll
        for (int mt = 0; mt < 2; ++mt) {
            short8 aa = *(const short8*)&adj[(g * 32 + mt * 16 + lrow) * LDA + kq];
            #pragma unroll
            for (int nl = 0; nl < 2; ++nl) {
                int col = (wv + nl * 4) * 16 + lrow;             // out col
                short8 bb = *(const short8*)&T1T[col * LDT + g * 32 + kq];
                f32x4 c = acc[g * 2 + mt][nl + 2];               // T2 init
                c = __builtin_amdgcn_mfma_f32_16x16x32_bf16(aa, bb, c, 0, 0, 0);
                int m0 = mt * 16 + (lane >> 4) * 4;
                float bias = nl ? b1 : b0;
                float* og = out + (size_t)(g0 + g) * 19 * 128 + col;
                #pragma unroll
                for (int r = 0; r < 4; ++r) {
                    int m = m0 + r;
                    if (m < 19) og[m * 128] = c[r] + bias;
                }
            }
        }
    }
}

extern "C" void kernel_launch(void* const* d_in, const int* in_sizes, int n_in,
                              void* d_out, int out_size, void* d_ws, size_t ws_size,
                              hipStream_t stream) {
    const float* x     = (const float*)d_in[0];
    const int*   ei    = (const int*)d_in[1];
    const float* ew    = (const float*)d_in[2];
    const float* Wrel  = (const float*)d_in[3];
    const float* brel  = (const float*)d_in[4];
    const float* Wroot = (const float*)d_in[5];
    float* out = (float*)d_out;
    unsigned short* wsW = (unsigned short*)d_ws;

    const int E_total  = in_sizes[1] / 2;     // 615600
    const int n_graphs = E_total / EPG;       // 1800

    conv_w<<<32, 256, 0, stream>>>(Wrel, Wroot, wsW);
    fused<<<n_graphs / 2, 256, 0, stream>>>(x, ei, ew, wsW, brel, out, E_total);
}